// Round 1
// baseline (266.819 us; speedup 1.0000x reference)
//
#include <hip/hip_runtime.h>
#include <hip/hip_bf16.h>

// Performer feature map: out[row][m] = exp( sum_k x[row][k]/scale * W[m][k] ) / sqrt(M)
// rows = B*H*L = 262144, K = D = 128, N = M = 128.
// Memory-bound GEMM (32 FLOP/byte): bf16 MFMA so compute is never the bottleneck.

typedef __attribute__((ext_vector_type(8))) short bf16x8;   // 8 bf16 = 4 VGPRs (MFMA A/B frag)
typedef __attribute__((ext_vector_type(4))) float f32x4;    // MFMA C/D frag
typedef __attribute__((ext_vector_type(4))) short short4v;

#define LDS_PITCH 136   // 128 + 8 bf16 pad: B-frag ds_read_b128 lands 8 accesses/bank (minimum)

__device__ __forceinline__ short f2bf(float f) {
    // round-to-nearest-even fp32 -> bf16 (inputs are finite gaussians; no NaN path needed)
    union { float f; unsigned u; } v; v.f = f;
    return (short)((v.u + 0x7fffu + ((v.u >> 16) & 1u)) >> 16);
}

__global__ __launch_bounds__(256, 4)
void performer_kernel(const float* __restrict__ x,
                      const float* __restrict__ Wf,
                      float* __restrict__ out,
                      int n_chunks) {   // chunk = 64 rows (4 waves x 16 rows)
    __shared__ short Wb[128 * LDS_PITCH];   // 34816 B -> 4 blocks/CU

    const int tid = threadIdx.x;

    // ---- Stage W -> LDS as bf16, scale 1/128^0.25 folded in. Coalesced float4 reads. ----
    {
        const float inv_scale = 0.29730177875068026f;  // 128^-0.25
        #pragma unroll
        for (int i = 0; i < 16; ++i) {
            int idx = i * 256 + tid;          // float4 index, 4096 total (128x128 fp32)
            int row = idx >> 5;               // 32 float4 per row
            int col = (idx & 31) << 2;        // column in floats
            float4 v = reinterpret_cast<const float4*>(Wf)[idx];
            short4v s;
            s.x = f2bf(v.x * inv_scale);
            s.y = f2bf(v.y * inv_scale);
            s.z = f2bf(v.z * inv_scale);
            s.w = f2bf(v.w * inv_scale);
            *reinterpret_cast<short4v*>(&Wb[row * LDS_PITCH + col]) = s;
        }
    }
    __syncthreads();

    const int wave = tid >> 6;       // 0..3
    const int lane = tid & 63;
    const int m    = lane & 15;      // A-row within 16-tile; also B-col within n-tile
    const int quad = lane >> 4;      // selects k-subblock of 8 for A/B frags; row group for C/D

    for (int chunk = blockIdx.x; chunk < n_chunks; chunk += gridDim.x) {
        const long row0 = (long)chunk * 64 + wave * 16;       // wave's 16-row tile base
        const float* xrow = x + (row0 + m) * 128 + quad * 8;

        // ---- Load A tile: 4 k-steps x 8 consecutive floats per lane (2x dwordx4 each) ----
        float4 av[4][2];
        #pragma unroll
        for (int ks = 0; ks < 4; ++ks) {
            const float4* p = reinterpret_cast<const float4*>(xrow + ks * 32);
            av[ks][0] = p[0];
            av[ks][1] = p[1];
        }
        // ---- Convert to bf16 A-frags: A[m=lane&15][k = ks*32 + quad*8 + j] ----
        bf16x8 af[4];
        #pragma unroll
        for (int ks = 0; ks < 4; ++ks) {
            af[ks][0] = f2bf(av[ks][0].x);
            af[ks][1] = f2bf(av[ks][0].y);
            af[ks][2] = f2bf(av[ks][0].z);
            af[ks][3] = f2bf(av[ks][0].w);
            af[ks][4] = f2bf(av[ks][1].x);
            af[ks][5] = f2bf(av[ks][1].y);
            af[ks][6] = f2bf(av[ks][1].z);
            af[ks][7] = f2bf(av[ks][1].w);
        }

        float* orow = out + row0 * 128;
        const float inv_sqrt_m = 0.08838834764831845f;  // 1/sqrt(128)

        #pragma unroll
        for (int nt = 0; nt < 8; ++nt) {
            // B-frag: B[k][n] = Wb[n][k], n = nt*16 + (lane&15), k = ks*32 + quad*8 + j
            bf16x8 bf[4];
            #pragma unroll
            for (int ks = 0; ks < 4; ++ks) {
                bf[ks] = *reinterpret_cast<const bf16x8*>(
                    &Wb[(nt * 16 + m) * LDS_PITCH + ks * 32 + quad * 8]);
            }
            f32x4 acc = {0.f, 0.f, 0.f, 0.f};
            #pragma unroll
            for (int ks = 0; ks < 4; ++ks)
                acc = __builtin_amdgcn_mfma_f32_16x16x32_bf16(af[ks], bf[ks], acc, 0, 0, 0);
            // C/D layout: col = lane&15 (= n within tile), row = quad*4 + reg
            #pragma unroll
            for (int r = 0; r < 4; ++r) {
                float v = __expf(acc[r]) * inv_sqrt_m;
                orow[(quad * 4 + r) * 128 + nt * 16 + m] = v;
            }
        }
    }
}

extern "C" void kernel_launch(void* const* d_in, const int* in_sizes, int n_in,
                              void* d_out, int out_size, void* d_ws, size_t ws_size,
                              hipStream_t stream) {
    const float* x  = (const float*)d_in[0];   // (B,H,L,D) fp32
    const float* Wf = (const float*)d_in[1];   // (M,D) fp32
    float* out = (float*)d_out;                // (B,H,L,M) fp32

    const int rows = out_size / 128;           // 262144
    const int n_chunks = rows / 64;            // 4096

    performer_kernel<<<dim3(1024), dim3(256), 0, stream>>>(x, Wf, out, n_chunks);
}

// Round 3
// 228.483 us; speedup vs baseline: 1.1678x; 1.1678x over previous
//
#include <hip/hip_runtime.h>
#include <hip/hip_bf16.h>

// Performer feature map: out[row][m] = exp( sum_k x[row][k]/scale * W[m][k] ) / sqrt(M)
// rows = B*H*L = 262144, K = D = 128, N = M = 128. Memory-bound (32 FLOP/byte).
// bf16 MFMA compute; LDS-transposed epilogue for full-line coalesced dwordx4 stores.

typedef __attribute__((ext_vector_type(8))) short bf16x8;   // MFMA A/B frag (4 VGPRs)
typedef __attribute__((ext_vector_type(4))) float f32x4;    // MFMA C/D frag + 16B vec ld/st
typedef __attribute__((ext_vector_type(4))) short short4v;

#define WPITCH 136   // shorts; 272 B rows: b128 B-frag reads 16B-aligned, 2-way bank (free)
#define OPITCH 68    // floats; 272 B rows: b128 readback 16B-aligned, exactly 8 acc/bank (min)

__device__ __forceinline__ short f2bf(float f) {
    // round-to-nearest-even fp32 -> bf16 (finite gaussian inputs; no NaN path)
    union { float f; unsigned u; } v; v.f = f;
    return (short)((v.u + 0x7fffu + ((v.u >> 16) & 1u)) >> 16);
}

__global__ __launch_bounds__(256)
void performer_kernel(const float* __restrict__ x,
                      const float* __restrict__ Wf,
                      float* __restrict__ out,
                      int n_chunks) {   // chunk = 64 rows (4 waves x 16 rows)
    __shared__ short Wb[128 * WPITCH];        // 34816 B
    __shared__ float Ob[4 * 16 * OPITCH];     // 17408 B (per-wave 16x64 transpose buffers)

    const int tid = threadIdx.x;

    // ---- Stage W -> LDS as bf16, scale 1/128^0.25 folded in. Coalesced float4 reads. ----
    {
        const float inv_scale = 0.29730177875068026f;  // 128^-0.25
        #pragma unroll
        for (int i = 0; i < 16; ++i) {
            int idx = i * 256 + tid;          // float4 index, 4096 total (128x128 fp32)
            int row = idx >> 5;
            int col = (idx & 31) << 2;
            f32x4 v = reinterpret_cast<const f32x4*>(Wf)[idx];
            short4v s;
            s.x = f2bf(v.x * inv_scale);
            s.y = f2bf(v.y * inv_scale);
            s.z = f2bf(v.z * inv_scale);
            s.w = f2bf(v.w * inv_scale);
            *reinterpret_cast<short4v*>(&Wb[row * WPITCH + col]) = s;
        }
    }
    __syncthreads();

    const int wave = tid >> 6;
    const int lane = tid & 63;
    const int m    = lane & 15;      // A-row within 16-tile; B-col within n-tile
    const int quad = lane >> 4;      // k-subblock select; C/D row group
    const int rrow = lane >> 3;      // epilogue readback: 8 lanes per row
    const int rcol = (lane & 7) * 4; // epilogue readback: float4 column
    float* obuf = &Ob[wave * 16 * OPITCH];
    const float inv_sqrt_m = 0.08838834764831845f;  // 1/sqrt(128)

    for (int chunk = blockIdx.x; chunk < n_chunks; chunk += gridDim.x) {
        const long row0 = (long)chunk * 64 + wave * 16;
        const float* xrow = x + (row0 + m) * 128 + quad * 8;

        // ---- A tile: 4 k-steps x 8 floats/lane (2x dwordx4, nontemporal: streamed) ----
        f32x4 av[4][2];
        #pragma unroll
        for (int ks = 0; ks < 4; ++ks) {
            const f32x4* p = reinterpret_cast<const f32x4*>(xrow + ks * 32);
            av[ks][0] = __builtin_nontemporal_load(p);
            av[ks][1] = __builtin_nontemporal_load(p + 1);
        }
        bf16x8 af[4];
        #pragma unroll
        for (int ks = 0; ks < 4; ++ks) {
            af[ks][0] = f2bf(av[ks][0].x);
            af[ks][1] = f2bf(av[ks][0].y);
            af[ks][2] = f2bf(av[ks][0].z);
            af[ks][3] = f2bf(av[ks][0].w);
            af[ks][4] = f2bf(av[ks][1].x);
            af[ks][5] = f2bf(av[ks][1].y);
            af[ks][6] = f2bf(av[ks][1].z);
            af[ks][7] = f2bf(av[ks][1].w);
        }

        // ---- 8 n-tiles of 16 cols: MFMA accumulate ----
        f32x4 acc[8];
        #pragma unroll
        for (int nt = 0; nt < 8; ++nt) {
            f32x4 a = {0.f, 0.f, 0.f, 0.f};
            #pragma unroll
            for (int ks = 0; ks < 4; ++ks) {
                bf16x8 bf = *reinterpret_cast<const bf16x8*>(
                    &Wb[(nt * 16 + m) * WPITCH + ks * 32 + quad * 8]);
                a = __builtin_amdgcn_mfma_f32_16x16x32_bf16(af[ks], bf, a, 0, 0, 0);
            }
            acc[nt] = a;
        }

        // ---- Epilogue: exp, transpose 16x64 half-tiles through LDS, dwordx4 stores ----
        float* orow = out + row0 * 128;
        #pragma unroll
        for (int h = 0; h < 2; ++h) {
            #pragma unroll
            for (int nt2 = 0; nt2 < 4; ++nt2) {
                #pragma unroll
                for (int r = 0; r < 4; ++r) {
                    // C/D layout: col = lane&15, row = quad*4 + r
                    obuf[(quad * 4 + r) * OPITCH + nt2 * 16 + m] =
                        __expf(acc[h * 4 + nt2][r]) * inv_sqrt_m;
                }
            }
            // same-wave LDS RAW/WAR: compiler inserts lgkmcnt waits
            #pragma unroll
            for (int rs = 0; rs < 2; ++rs) {
                #pragma unroll
                for (int j = 0; j < 2; ++j) {
                    f32x4 v = *reinterpret_cast<const f32x4*>(
                        &obuf[(rs * 8 + rrow) * OPITCH + j * 32 + rcol]);
                    // per store instr: 8 rows x 128 B contiguous aligned segments
                    __builtin_nontemporal_store(v, reinterpret_cast<f32x4*>(
                        &orow[(rs * 8 + rrow) * 128 + h * 64 + j * 32 + rcol]));
                }
            }
        }
    }
}

extern "C" void kernel_launch(void* const* d_in, const int* in_sizes, int n_in,
                              void* d_out, int out_size, void* d_ws, size_t ws_size,
                              hipStream_t stream) {
    const float* x  = (const float*)d_in[0];   // (B,H,L,D) fp32
    const float* Wf = (const float*)d_in[1];   // (M,D) fp32
    float* out = (float*)d_out;                // (B,H,L,M) fp32

    const int rows = out_size / 128;           // 262144
    const int n_chunks = rows / 64;            // 4096

    performer_kernel<<<dim3(1024), dim3(256), 0, stream>>>(x, Wf, out, n_chunks);
}